// Round 1
// baseline (1212.547 us; speedup 1.0000x reference)
//
#include <hip/hip_runtime.h>
#include <math.h>

#define SEQL   2048
#define DIMM   1024
#define NST    16
#define INR    2048
#define TOKS   4096   // BATCH*SEQL

// ------------------------------------------------------------------
// W_x (33 x INR) -> W_xT (INR x 33) so the ssm kernel gets contiguous
// (scalar-loadable) weight rows per channel.
__global__ __launch_bounds__(256) void k_wxt(const float* __restrict__ Wx,
                                             float* __restrict__ WxT)
{
    int i = blockIdx.x * 256 + threadIdx.x;   // over 33*INR
    if (i < 33 * INR) {
        int j = i / INR, ch = i % INR;
        WxT[ch * 33 + j] = Wx[i];
    }
}

// ------------------------------------------------------------------
// GEMM1: xr = x @ W_in.T   (M=4096, K=1024, N=4096), NT, fp32 vector.
// n <  INR -> u0 (pre-conv)
// n >= INR -> sres = silu(res)
// 128x128 tile, BK=8, 256 threads, 8x8 per thread.
__global__ __launch_bounds__(256) void k_gemm1(const float* __restrict__ X,
        const float* __restrict__ Win, float* __restrict__ u0,
        float* __restrict__ sres)
{
    __shared__ float As[8][132];
    __shared__ float Bs[8][132];
    const int tid = threadIdx.x;
    const int m0 = blockIdx.y * 128, n0 = blockIdx.x * 128;
    const int tx = tid & 15, ty = tid >> 4;
    const int lr = tid >> 1, lk = (tid & 1) * 4;
    const float* Ap = X   + (size_t)(m0 + lr) * DIMM + lk;
    const float* Bp = Win + (size_t)(n0 + lr) * DIMM + lk;
    float acc[8][8];
    #pragma unroll
    for (int i = 0; i < 8; ++i)
        #pragma unroll
        for (int j = 0; j < 8; ++j) acc[i][j] = 0.f;

    for (int k0 = 0; k0 < DIMM; k0 += 8) {
        float4 av = *(const float4*)(Ap + k0);
        float4 bv = *(const float4*)(Bp + k0);
        __syncthreads();
        As[lk+0][lr]=av.x; As[lk+1][lr]=av.y; As[lk+2][lr]=av.z; As[lk+3][lr]=av.w;
        Bs[lk+0][lr]=bv.x; Bs[lk+1][lr]=bv.y; Bs[lk+2][lr]=bv.z; Bs[lk+3][lr]=bv.w;
        __syncthreads();
        #pragma unroll
        for (int kk = 0; kk < 8; ++kk) {
            float a[8], b[8];
            *(float4*)&a[0] = *(const float4*)&As[kk][ty*8];
            *(float4*)&a[4] = *(const float4*)&As[kk][ty*8+4];
            *(float4*)&b[0] = *(const float4*)&Bs[kk][tx*4];
            *(float4*)&b[4] = *(const float4*)&Bs[kk][64 + tx*4];
            #pragma unroll
            for (int i = 0; i < 8; ++i)
                #pragma unroll
                for (int j = 0; j < 8; ++j)
                    acc[i][j] = fmaf(a[i], b[j], acc[i][j]);
        }
    }
    const bool isres = (n0 >= INR);
    float* dst = isres ? sres : u0;
    const int nb = isres ? (n0 - INR) : n0;
    #pragma unroll
    for (int i = 0; i < 8; ++i) {
        size_t row = (size_t)(m0 + ty*8 + i) * INR;
        float o[8];
        #pragma unroll
        for (int j = 0; j < 8; ++j) {
            float v = acc[i][j];
            if (isres) v = v / (1.f + __expf(-v));   // silu
            o[j] = v;
        }
        *(float4*)&dst[row + nb + tx*4]      = *(float4*)&o[0];
        *(float4*)&dst[row + nb + 64 + tx*4] = *(float4*)&o[4];
    }
}

// ------------------------------------------------------------------
// Depthwise causal conv (K=4) + bias; reads u0 [tok][ch],
// writes channel-major uct [b][ch][t] for the scan.
__global__ __launch_bounds__(256) void k_conv(const float* __restrict__ u0,
        const float* __restrict__ cw, const float* __restrict__ cb,
        float* __restrict__ uct)
{
    __shared__ float S[67][65];
    const int tid = threadIdx.x;
    const int ch0 = blockIdx.x * 64;
    const int t0  = blockIdx.y * 64;
    const int b   = blockIdx.z;
    const int ci  = tid & 63;
    for (int r = tid >> 6; r < 67; r += 4) {
        int t = t0 - 3 + r;
        S[r][ci] = (t < 0) ? 0.f : u0[((size_t)b*SEQL + t)*INR + ch0 + ci];
    }
    __syncthreads();
    const int ti = tid & 63;
    const int cq = tid >> 6;
    #pragma unroll
    for (int q = 0; q < 16; ++q) {
        int c  = cq + q*4;
        int ch = ch0 + c;
        float w0 = cw[ch*4+0], w1 = cw[ch*4+1], w2 = cw[ch*4+2], w3 = cw[ch*4+3];
        float acc = cb[ch]
            + w0*S[ti+0][c] + w1*S[ti+1][c] + w2*S[ti+2][c] + w3*S[ti+3][c];
        uct[((size_t)b*INR + ch)*SEQL + t0 + ti] = acc;
    }
}

// ------------------------------------------------------------------
// ssm = u @ W_x.T : reduce over channels, split 8 ways -> partials.
__global__ __launch_bounds__(256) void k_ssm_part(const float* __restrict__ uct,
        const float* __restrict__ WxT, float* __restrict__ part)
{
    const int t  = blockIdx.x * 256 + threadIdx.x;  // 0..SEQL-1
    const int cs = blockIdx.y;                      // 0..7
    const int b  = blockIdx.z;
    const int ch0 = cs * 256;
    float acc[33];
    #pragma unroll
    for (int j = 0; j < 33; ++j) acc[j] = 0.f;
    const float* up = uct + ((size_t)b*INR + ch0)*SEQL + t;
    for (int c = 0; c < 256; ++c) {
        float uv = up[(size_t)c * SEQL];
        const float* wr = WxT + (size_t)(ch0 + c) * 33;   // uniform -> s_loads
        #pragma unroll
        for (int j = 0; j < 33; ++j) acc[j] = fmaf(uv, wr[j], acc[j]);
    }
    #pragma unroll
    for (int j = 0; j < 33; ++j)
        part[(((size_t)j*8 + cs)*2 + b)*SEQL + t] = acc[j];
}

__global__ __launch_bounds__(256) void k_ssm_reduce(const float* __restrict__ part,
        float* __restrict__ dtin, float* __restrict__ Bm, float* __restrict__ Cv)
{
    int g = blockIdx.x * 256 + threadIdx.x;   // over 33*TOKS
    if (g >= 33 * TOKS) return;
    int j = g / TOKS, m = g % TOKS;
    int b = m >> 11, t = m & 2047;
    float s = 0.f;
    #pragma unroll
    for (int cs = 0; cs < 8; ++cs)
        s += part[(((size_t)j*8 + cs)*2 + b)*SEQL + t];
    if (j < 16)      dtin[m*16 + j] = s;
    else if (j < 32) Bm[m*16 + (j-16)] = s;
    else             Cv[m] = s;
}

// ------------------------------------------------------------------
// delta = softplus(dt_in @ W_dt.T + b_dt), written channel-major
// dT [b][ch][t].  64x64 tile, K=16.
__global__ __launch_bounds__(256) void k_delta(const float* __restrict__ dtin,
        const float* __restrict__ Wdt, const float* __restrict__ bdt,
        float* __restrict__ dT)
{
    __shared__ float Ds[16][68];
    __shared__ float Ws[16][68];
    const int tid = threadIdx.x;
    const int c0 = blockIdx.x * 64;   // channel tile
    const int m0 = blockIdx.y * 64;   // token tile (never straddles batch)
    const int r = tid >> 2, kq = (tid & 3) * 4;
    {
        float4 dv = *(const float4*)&dtin[(size_t)(m0 + r)*16 + kq];
        float4 wv = *(const float4*)&Wdt [(size_t)(c0 + r)*16 + kq];
        Ds[kq+0][r]=dv.x; Ds[kq+1][r]=dv.y; Ds[kq+2][r]=dv.z; Ds[kq+3][r]=dv.w;
        Ws[kq+0][r]=wv.x; Ws[kq+1][r]=wv.y; Ws[kq+2][r]=wv.z; Ws[kq+3][r]=wv.w;
    }
    __syncthreads();
    const int tx = tid & 15, ty = tid >> 4;   // tx: ch quads, ty: token quads
    float acc[4][4];
    #pragma unroll
    for (int i = 0; i < 4; ++i)
        #pragma unroll
        for (int j = 0; j < 4; ++j) acc[i][j] = 0.f;
    #pragma unroll
    for (int kk = 0; kk < 16; ++kk) {
        float4 a4 = *(const float4*)&Ds[kk][ty*4];
        float4 b4 = *(const float4*)&Ws[kk][tx*4];
        float a[4] = {a4.x, a4.y, a4.z, a4.w};
        float w[4] = {b4.x, b4.y, b4.z, b4.w};
        #pragma unroll
        for (int i = 0; i < 4; ++i)
            #pragma unroll
            for (int j = 0; j < 4; ++j)
                acc[i][j] = fmaf(a[i], w[j], acc[i][j]);
    }
    const int b = m0 >> 11;
    const int tbase = (m0 & 2047) + ty*4;
    #pragma unroll
    for (int j = 0; j < 4; ++j) {
        int ch = c0 + tx*4 + j;
        float bias = bdt[ch];
        float4 o;
        o.x = log1pf(__expf(acc[0][j] + bias));
        o.y = log1pf(__expf(acc[1][j] + bias));
        o.z = log1pf(__expf(acc[2][j] + bias));
        o.w = log1pf(__expf(acc[3][j] + bias));
        *(float4*)&dT[((size_t)b*INR + ch)*SEQL + tbase] = o;
    }
}

// ------------------------------------------------------------------
// Sequential selective scan. 16 lanes per channel (one state each),
// 16 channels per 256-thread block. 64-step chunks staged in LDS.
__global__ __launch_bounds__(256) void k_scan(const float* __restrict__ dT,
        const float* __restrict__ uct, const float* __restrict__ Bm,
        const float* __restrict__ Cv, const float* __restrict__ Alog,
        float* __restrict__ Y)
{
    __shared__ float dS[16][68];
    __shared__ float uS[16][68];
    __shared__ float yS[16][68];
    __shared__ float bS[64*16];
    __shared__ float cS[64];
    const int tid = threadIdx.x;
    const int g = tid >> 4, s = tid & 15;
    const int b = blockIdx.y;
    const int ch0 = blockIdx.x * 16;
    const int ch = ch0 + g;
    const float A = -__expf(Alog[ch*NST + s]);
    float h = 0.f;
    const int row = tid >> 4, col4 = (tid & 15) * 4;
    const size_t mb = (size_t)b * SEQL;
    const float* dRow = dT  + ((size_t)b*INR + ch0 + row)*SEQL;
    const float* uRow = uct + ((size_t)b*INR + ch0 + row)*SEQL;

    for (int t0 = 0; t0 < SEQL; t0 += 64) {
        __syncthreads();
        *(float4*)&dS[row][col4] = *(const float4*)&dRow[t0 + col4];
        *(float4*)&uS[row][col4] = *(const float4*)&uRow[t0 + col4];
        ((float4*)bS)[tid] = *(const float4*)&Bm[(mb + t0)*16 + tid*4];
        if (tid < 64) cS[tid] = Cv[mb + t0 + tid];
        __syncthreads();
        #pragma unroll 8
        for (int ti = 0; ti < 64; ++ti) {
            float e = __expf(dS[g][ti] * A);
            h = fmaf(h, e, uS[g][ti] * bS[ti*16 + s]);
            float v = h;
            v += __shfl_xor(v, 1);
            v += __shfl_xor(v, 2);
            v += __shfl_xor(v, 4);
            v += __shfl_xor(v, 8);
            if (s == 0) yS[g][ti] = v * cS[ti];
        }
        __syncthreads();
        const int ci = tid & 15, tw = tid >> 4;
        #pragma unroll
        for (int rr = 0; rr < 4; ++rr) {
            int t = t0 + tw + rr*16;
            Y[(mb + t)*INR + ch0 + ci] = yS[ci][tw + rr*16];
        }
    }
}

// ------------------------------------------------------------------
// out = (y * sres) @ W_out.T   (M=4096, K=2048, N=1024)
// 64x128 tile, BK=16, 256 threads, 4x8 per thread. A-load fuses y*sres.
__global__ __launch_bounds__(256) void k_gemmout(const float* __restrict__ Yv,
        const float* __restrict__ Sv, const float* __restrict__ Wo,
        float* __restrict__ out)
{
    __shared__ float As[16][68];
    __shared__ float Bs[16][132];
    const int tid = threadIdx.x;
    const int n0 = blockIdx.x * 128, m0 = blockIdx.y * 64;
    const int tx = tid & 15, ty = tid >> 4;
    const int ra = tid >> 2, ka = (tid & 3) * 4;   // A: 64 rows x 16 k
    const int rb = tid >> 1, kb = (tid & 1) * 8;   // B: 128 rows x 16 k
    const float* Yp = Yv + (size_t)(m0 + ra)*INR + ka;
    const float* Sp = Sv + (size_t)(m0 + ra)*INR + ka;
    const float* Bp = Wo + (size_t)(n0 + rb)*INR + kb;
    float acc[4][8];
    #pragma unroll
    for (int i = 0; i < 4; ++i)
        #pragma unroll
        for (int j = 0; j < 8; ++j) acc[i][j] = 0.f;

    for (int k0 = 0; k0 < INR; k0 += 16) {
        float4 yv = *(const float4*)(Yp + k0);
        float4 sv = *(const float4*)(Sp + k0);
        float4 b0 = *(const float4*)(Bp + k0);
        float4 b1 = *(const float4*)(Bp + k0 + 4);
        float4 av;
        av.x = yv.x*sv.x; av.y = yv.y*sv.y; av.z = yv.z*sv.z; av.w = yv.w*sv.w;
        __syncthreads();
        As[ka+0][ra]=av.x; As[ka+1][ra]=av.y; As[ka+2][ra]=av.z; As[ka+3][ra]=av.w;
        Bs[kb+0][rb]=b0.x; Bs[kb+1][rb]=b0.y; Bs[kb+2][rb]=b0.z; Bs[kb+3][rb]=b0.w;
        Bs[kb+4][rb]=b1.x; Bs[kb+5][rb]=b1.y; Bs[kb+6][rb]=b1.z; Bs[kb+7][rb]=b1.w;
        __syncthreads();
        #pragma unroll
        for (int kk = 0; kk < 16; ++kk) {
            float a[4], w[8];
            *(float4*)&a[0] = *(const float4*)&As[kk][ty*4];
            *(float4*)&w[0] = *(const float4*)&Bs[kk][tx*4];
            *(float4*)&w[4] = *(const float4*)&Bs[kk][64 + tx*4];
            #pragma unroll
            for (int i = 0; i < 4; ++i)
                #pragma unroll
                for (int j = 0; j < 8; ++j)
                    acc[i][j] = fmaf(a[i], w[j], acc[i][j]);
        }
    }
    #pragma unroll
    for (int i = 0; i < 4; ++i) {
        size_t row = (size_t)(m0 + ty*4 + i) * DIMM;
        *(float4*)&out[row + n0 + tx*4]      = *(float4*)&acc[i][0];
        *(float4*)&out[row + n0 + 64 + tx*4] = *(float4*)&acc[i][4];
    }
}

// ------------------------------------------------------------------
extern "C" void kernel_launch(void* const* d_in, const int* in_sizes, int n_in,
                              void* d_out, int out_size, void* d_ws, size_t ws_size,
                              hipStream_t stream)
{
    (void)in_sizes; (void)n_in; (void)out_size; (void)ws_size;
    const float* x     = (const float*)d_in[0];
    const float* W_in  = (const float*)d_in[1];
    const float* cw    = (const float*)d_in[2];
    const float* cb    = (const float*)d_in[3];
    const float* W_x   = (const float*)d_in[4];
    const float* W_dt  = (const float*)d_in[5];
    const float* b_dt  = (const float*)d_in[6];
    const float* W_out = (const float*)d_in[7];
    const float* A_log = (const float*)d_in[8];
    float* out = (float*)d_out;

    float* ws = (float*)d_ws;
    const size_t MI = 1024 * 1024;
    float* u0   = ws;                // 8Mi floats; reused as delta_T after conv
    float* sres = ws + 8*MI;         // 8Mi
    float* uct  = ws + 16*MI;        // 8Mi
    float* y    = ws + 24*MI;        // 8Mi; holds ssm partials before scan
    float* part = y;                 // 33*8*2*2048 = 1.08Mi floats, fits
    float* dtin = ws + 32*MI;        // 64Ki
    float* Bm   = dtin + 65536;      // 64Ki
    float* Cv   = Bm + 65536;        // 4Ki
    float* WxT  = Cv + 4096;         // 66Ki
    float* dT   = u0;

    k_wxt       <<<dim3((33*INR + 255)/256), 256, 0, stream>>>(W_x, WxT);
    k_gemm1     <<<dim3(32, 32),             256, 0, stream>>>(x, W_in, u0, sres);
    k_conv      <<<dim3(32, 32, 2),          256, 0, stream>>>(u0, cw, cb, uct);
    k_ssm_part  <<<dim3(8, 8, 2),            256, 0, stream>>>(uct, WxT, part);
    k_ssm_reduce<<<dim3((33*TOKS + 255)/256),256, 0, stream>>>(part, dtin, Bm, Cv);
    k_delta     <<<dim3(32, 64),             256, 0, stream>>>(dtin, W_dt, b_dt, dT);
    k_scan      <<<dim3(128, 2),             256, 0, stream>>>(dT, uct, Bm, Cv, A_log, y);
    k_gemmout   <<<dim3(8, 64),              256, 0, stream>>>(y, sres, W_out, out);
}

// Round 2
// 738.198 us; speedup vs baseline: 1.6426x; 1.6426x over previous
//
#include <hip/hip_runtime.h>
#include <math.h>

#define SEQL   2048
#define DIMM   1024
#define NST    16
#define INR    2048
#define TOKS   4096   // BATCH*SEQL

typedef _Float16 f16;
typedef _Float16 f16x8 __attribute__((ext_vector_type(8)));
typedef float    f32x4 __attribute__((ext_vector_type(4)));

__device__ __forceinline__ int swz(int r) { return (r & 3) ^ ((r >> 2) & 3); }

#define GLDS(SRC, DST) __builtin_amdgcn_global_load_lds( \
    (const __attribute__((address_space(1))) void*)(SRC), \
    (__attribute__((address_space(3))) void*)(DST), 16, 0, 0)

// ------------------------------------------------------------------
// W_x (33 x INR) -> W_xT (INR x 33)
__global__ __launch_bounds__(256) void k_wxt(const float* __restrict__ Wx,
                                             float* __restrict__ WxT)
{
    int i = blockIdx.x * 256 + threadIdx.x;
    if (i < 33 * INR) {
        int j = i / INR, ch = i % INR;
        WxT[ch * 33 + j] = Wx[i];
    }
}

// ------------------------------------------------------------------
// fp32 -> (hi fp16, lo fp16 scaled by 2048)
__global__ __launch_bounds__(256) void k_cvt_pair(const float* __restrict__ in,
        f16* __restrict__ hi, f16* __restrict__ lo, int n8)
{
    int i = blockIdx.x * 256 + threadIdx.x;
    if (i >= n8) return;
    const float4* p = (const float4*)(in + (size_t)i * 8);
    float4 a = p[0], b = p[1];
    float v[8] = {a.x, a.y, a.z, a.w, b.x, b.y, b.z, b.w};
    f16x8 H, L;
    #pragma unroll
    for (int j = 0; j < 8; ++j) {
        f16 h = (f16)v[j];
        float r = v[j] - (float)h;
        H[j] = h;
        L[j] = (f16)(r * 2048.f);
    }
    *(f16x8*)(hi + (size_t)i * 8) = H;
    *(f16x8*)(lo + (size_t)i * 8) = L;
}

// same, but input = y * sres (fused elementwise product)
__global__ __launch_bounds__(256) void k_cvt_mul(const float* __restrict__ ya,
        const float* __restrict__ sa, f16* __restrict__ hi, f16* __restrict__ lo,
        int n8)
{
    int i = blockIdx.x * 256 + threadIdx.x;
    if (i >= n8) return;
    const float4* py = (const float4*)(ya + (size_t)i * 8);
    const float4* ps = (const float4*)(sa + (size_t)i * 8);
    float4 a = py[0], b = py[1], c = ps[0], d = ps[1];
    float v[8] = {a.x*c.x, a.y*c.y, a.z*c.z, a.w*c.w,
                  b.x*d.x, b.y*d.y, b.z*d.z, b.w*d.w};
    f16x8 H, L;
    #pragma unroll
    for (int j = 0; j < 8; ++j) {
        f16 h = (f16)v[j];
        float r = v[j] - (float)h;
        H[j] = h;
        L[j] = (f16)(r * 2048.f);
    }
    *(f16x8*)(hi + (size_t)i * 8) = H;
    *(f16x8*)(lo + (size_t)i * 8) = L;
}

// ------------------------------------------------------------------
// Split-fp16 MFMA GEMM (NT): C[M][N] = A[M][K] * B[N][K]^T in ~fp32 accuracy.
// Tile 128(m) x 64(n), BK=32, 4 waves (2x2), wave tile 64x32 = 4x2 frags.
// 3 MFMA per frag pair: hh -> acc0 ; hl + lh -> acc1 (scaled 2^-11 at end).
// LDS planes [rows][4 slots][8 f16] with XOR chunk swizzle on both sides.
// epi=1: N=4096, col<2048 -> out0 (raw), col>=2048 -> out1 (silu).
// epi=0: plain store to out0 with row stride Nst.
__global__ __launch_bounds__(256, 3) void k_gemm_split(
        const f16* __restrict__ Ah, const f16* __restrict__ Al,
        const f16* __restrict__ Bh, const f16* __restrict__ Bl,
        int K, int epi, int Nst,
        float* __restrict__ out0, float* __restrict__ out1)
{
    // plane offsets in f16 elems
    const int AHI = 0, ALO = 4096, BHI = 8192, BLO = 10240;
    __shared__ alignas(16) f16 SM[12288];   // 24 KB

    const int tid = threadIdx.x;
    const int l   = tid & 63;
    const int w   = tid >> 6;
    const int wm  = (w >> 1) * 64;
    const int wn  = (w & 1) * 32;
    const int lr  = l & 15;
    const int kg  = l >> 4;
    const int m0  = blockIdx.y * 128;
    const int n0  = blockIdx.x * 64;

    // staging lane constants: 16 rows x 4 slots per wave-call
    const int srow = l >> 2;
    const int sc   = (l & 3) ^ swz(srow);     // swizzled source chunk
    const int w16  = w * 16;
    // fragment-read lane offset (elems within a plane, row-block added later)
    const int fo   = lr * 32 + (kg ^ swz(lr)) * 8;

    f32x4 acc0[4][2], acc1[4][2];
    #pragma unroll
    for (int mi = 0; mi < 4; ++mi)
        #pragma unroll
        for (int ni = 0; ni < 2; ++ni) {
            acc0[mi][ni] = (f32x4){0.f, 0.f, 0.f, 0.f};
            acc1[mi][ni] = (f32x4){0.f, 0.f, 0.f, 0.f};
        }

    for (int k0 = 0; k0 < K; k0 += 32) {
        __syncthreads();
        // ---- stage A (128 rows x 32) hi+lo, B (64 rows x 32) hi+lo
        #pragma unroll
        for (int q = 0; q < 2; ++q) {
            const int rl = q * 64 + w16 + srow;
            const size_t go = (size_t)(m0 + rl) * K + k0 + sc * 8;
            GLDS(Ah + go, &SM[AHI + (q * 64 + w16) * 32]);
            GLDS(Al + go, &SM[ALO + (q * 64 + w16) * 32]);
        }
        {
            const int rl = w16 + srow;
            const size_t go = (size_t)(n0 + rl) * K + k0 + sc * 8;
            GLDS(Bh + go, &SM[BHI + w16 * 32]);
            GLDS(Bl + go, &SM[BLO + w16 * 32]);
        }
        __syncthreads();

        // ---- fragments
        f16x8 ah[4], al4[4], bh[2], bl[2];
        #pragma unroll
        for (int mi = 0; mi < 4; ++mi) {
            int off = (wm + mi * 16) * 32 + fo;
            ah[mi]  = *(const f16x8*)&SM[AHI + off];
            al4[mi] = *(const f16x8*)&SM[ALO + off];
        }
        #pragma unroll
        for (int ni = 0; ni < 2; ++ni) {
            int off = (wn + ni * 16) * 32 + fo;
            bh[ni] = *(const f16x8*)&SM[BHI + off];
            bl[ni] = *(const f16x8*)&SM[BLO + off];
        }
        // ---- 24 MFMA
        #pragma unroll
        for (int mi = 0; mi < 4; ++mi)
            #pragma unroll
            for (int ni = 0; ni < 2; ++ni) {
                acc0[mi][ni] = __builtin_amdgcn_mfma_f32_16x16x32_f16(
                                   ah[mi], bh[ni], acc0[mi][ni], 0, 0, 0);
                acc1[mi][ni] = __builtin_amdgcn_mfma_f32_16x16x32_f16(
                                   ah[mi], bl[ni], acc1[mi][ni], 0, 0, 0);
                acc1[mi][ni] = __builtin_amdgcn_mfma_f32_16x16x32_f16(
                                   al4[mi], bh[ni], acc1[mi][ni], 0, 0, 0);
            }
    }

    // ---- epilogue: C/D layout col=lane&15, row=(lane>>4)*4+reg
    const int r0 = (l >> 4) * 4;
    #pragma unroll
    for (int mi = 0; mi < 4; ++mi)
        #pragma unroll
        for (int ni = 0; ni < 2; ++ni) {
            const int col = n0 + wn + ni * 16 + (l & 15);
            #pragma unroll
            for (int rr = 0; rr < 4; ++rr) {
                const int row = m0 + wm + mi * 16 + r0 + rr;
                float v = acc0[mi][ni][rr] + acc1[mi][ni][rr] * (1.0f / 2048.0f);
                if (epi) {
                    if (col < INR) {
                        out0[(size_t)row * INR + col] = v;
                    } else {
                        float s = v / (1.f + __expf(-v));
                        out1[(size_t)row * INR + (col - INR)] = s;
                    }
                } else {
                    out0[(size_t)row * Nst + col] = v;
                }
            }
        }
}

// ------------------------------------------------------------------
// Depthwise causal conv (K=4) + bias; u0 [tok][ch] -> uct [b][ch][t]
__global__ __launch_bounds__(256) void k_conv(const float* __restrict__ u0,
        const float* __restrict__ cw, const float* __restrict__ cb,
        float* __restrict__ uct)
{
    __shared__ float S[67][65];
    const int tid = threadIdx.x;
    const int ch0 = blockIdx.x * 64;
    const int t0  = blockIdx.y * 64;
    const int b   = blockIdx.z;
    const int ci  = tid & 63;
    for (int r = tid >> 6; r < 67; r += 4) {
        int t = t0 - 3 + r;
        S[r][ci] = (t < 0) ? 0.f : u0[((size_t)b*SEQL + t)*INR + ch0 + ci];
    }
    __syncthreads();
    const int ti = tid & 63;
    const int cq = tid >> 6;
    #pragma unroll
    for (int q = 0; q < 16; ++q) {
        int c  = cq + q*4;
        int ch = ch0 + c;
        float w0 = cw[ch*4+0], w1 = cw[ch*4+1], w2 = cw[ch*4+2], w3 = cw[ch*4+3];
        float acc = cb[ch]
            + w0*S[ti+0][c] + w1*S[ti+1][c] + w2*S[ti+2][c] + w3*S[ti+3][c];
        uct[((size_t)b*INR + ch)*SEQL + t0 + ti] = acc;
    }
}

// ------------------------------------------------------------------
// ssm = u @ W_x.T : reduce over channels, 16-way split -> partials.
__global__ __launch_bounds__(256) void k_ssm_part(const float* __restrict__ uct,
        const float* __restrict__ WxT, float* __restrict__ part)
{
    const int t  = blockIdx.x * 256 + threadIdx.x;
    const int cs = blockIdx.y;                      // 0..15
    const int b  = blockIdx.z;
    const int ch0 = cs * 128;
    float acc[33];
    #pragma unroll
    for (int j = 0; j < 33; ++j) acc[j] = 0.f;
    const float* up = uct + ((size_t)b*INR + ch0)*SEQL + t;
    for (int c = 0; c < 128; ++c) {
        float uv = up[(size_t)c * SEQL];
        const float* wr = WxT + (size_t)(ch0 + c) * 33;
        #pragma unroll
        for (int j = 0; j < 33; ++j) acc[j] = fmaf(uv, wr[j], acc[j]);
    }
    #pragma unroll
    for (int j = 0; j < 33; ++j)
        part[(((size_t)j*16 + cs)*2 + b)*SEQL + t] = acc[j];
}

__global__ __launch_bounds__(256) void k_ssm_reduce(const float* __restrict__ part,
        float* __restrict__ dtin, float* __restrict__ Bm, float* __restrict__ Cv)
{
    int g = blockIdx.x * 256 + threadIdx.x;
    if (g >= 33 * TOKS) return;
    int j = g / TOKS, m = g % TOKS;
    int b = m >> 11, t = m & 2047;
    float s = 0.f;
    #pragma unroll
    for (int cs = 0; cs < 16; ++cs)
        s += part[(((size_t)j*16 + cs)*2 + b)*SEQL + t];
    if (j < 16)      dtin[m*16 + j] = s;
    else if (j < 32) Bm[m*16 + (j-16)] = s;
    else             Cv[m] = s;
}

// ------------------------------------------------------------------
// delta = softplus(dt_in @ W_dt.T + b_dt) -> dT [b][ch][t]
__global__ __launch_bounds__(256) void k_delta(const float* __restrict__ dtin,
        const float* __restrict__ Wdt, const float* __restrict__ bdt,
        float* __restrict__ dT)
{
    __shared__ float Ds[16][68];
    __shared__ float Ws[16][68];
    const int tid = threadIdx.x;
    const int c0 = blockIdx.x * 64;
    const int m0 = blockIdx.y * 64;
    const int r = tid >> 2, kq = (tid & 3) * 4;
    {
        float4 dv = *(const float4*)&dtin[(size_t)(m0 + r)*16 + kq];
        float4 wv = *(const float4*)&Wdt [(size_t)(c0 + r)*16 + kq];
        Ds[kq+0][r]=dv.x; Ds[kq+1][r]=dv.y; Ds[kq+2][r]=dv.z; Ds[kq+3][r]=dv.w;
        Ws[kq+0][r]=wv.x; Ws[kq+1][r]=wv.y; Ws[kq+2][r]=wv.z; Ws[kq+3][r]=wv.w;
    }
    __syncthreads();
    const int tx = tid & 15, ty = tid >> 4;
    float acc[4][4];
    #pragma unroll
    for (int i = 0; i < 4; ++i)
        #pragma unroll
        for (int j = 0; j < 4; ++j) acc[i][j] = 0.f;
    #pragma unroll
    for (int kk = 0; kk < 16; ++kk) {
        float4 a4 = *(const float4*)&Ds[kk][ty*4];
        float4 b4 = *(const float4*)&Ws[kk][tx*4];
        float a[4] = {a4.x, a4.y, a4.z, a4.w};
        float wv[4] = {b4.x, b4.y, b4.z, b4.w};
        #pragma unroll
        for (int i = 0; i < 4; ++i)
            #pragma unroll
            for (int j = 0; j < 4; ++j)
                acc[i][j] = fmaf(a[i], wv[j], acc[i][j]);
    }
    const int b = m0 >> 11;
    const int tbase = (m0 & 2047) + ty*4;
    #pragma unroll
    for (int j = 0; j < 4; ++j) {
        int ch = c0 + tx*4 + j;
        float bias = bdt[ch];
        float4 o;
        o.x = log1pf(__expf(acc[0][j] + bias));
        o.y = log1pf(__expf(acc[1][j] + bias));
        o.z = log1pf(__expf(acc[2][j] + bias));
        o.w = log1pf(__expf(acc[3][j] + bias));
        *(float4*)&dT[((size_t)b*INR + ch)*SEQL + tbase] = o;
    }
}

// ------------------------------------------------------------------
// Sequential selective scan (unchanged)
__global__ __launch_bounds__(256) void k_scan(const float* __restrict__ dT,
        const float* __restrict__ uct, const float* __restrict__ Bm,
        const float* __restrict__ Cv, const float* __restrict__ Alog,
        float* __restrict__ Y)
{
    __shared__ float dS[16][68];
    __shared__ float uS[16][68];
    __shared__ float yS[16][68];
    __shared__ float bS[64*16];
    __shared__ float cS[64];
    const int tid = threadIdx.x;
    const int g = tid >> 4, s = tid & 15;
    const int b = blockIdx.y;
    const int ch0 = blockIdx.x * 16;
    const int ch = ch0 + g;
    const float A = -__expf(Alog[ch*NST + s]);
    float h = 0.f;
    const int row = tid >> 4, col4 = (tid & 15) * 4;
    const size_t mb = (size_t)b * SEQL;
    const float* dRow = dT  + ((size_t)b*INR + ch0 + row)*SEQL;
    const float* uRow = uct + ((size_t)b*INR + ch0 + row)*SEQL;

    for (int t0 = 0; t0 < SEQL; t0 += 64) {
        __syncthreads();
        *(float4*)&dS[row][col4] = *(const float4*)&dRow[t0 + col4];
        *(float4*)&uS[row][col4] = *(const float4*)&uRow[t0 + col4];
        ((float4*)bS)[tid] = *(const float4*)&Bm[(mb + t0)*16 + tid*4];
        if (tid < 64) cS[tid] = Cv[mb + t0 + tid];
        __syncthreads();
        #pragma unroll 8
        for (int ti = 0; ti < 64; ++ti) {
            float e = __expf(dS[g][ti] * A);
            h = fmaf(h, e, uS[g][ti] * bS[ti*16 + s]);
            float v = h;
            v += __shfl_xor(v, 1);
            v += __shfl_xor(v, 2);
            v += __shfl_xor(v, 4);
            v += __shfl_xor(v, 8);
            if (s == 0) yS[g][ti] = v * cS[ti];
        }
        __syncthreads();
        const int ci = tid & 15, tw = tid >> 4;
        #pragma unroll
        for (int rr = 0; rr < 4; ++rr) {
            int t = t0 + tw + rr*16;
            Y[(mb + t)*INR + ch0 + ci] = yS[ci][tw + rr*16];
        }
    }
}

// ------------------------------------------------------------------
extern "C" void kernel_launch(void* const* d_in, const int* in_sizes, int n_in,
                              void* d_out, int out_size, void* d_ws, size_t ws_size,
                              hipStream_t stream)
{
    (void)in_sizes; (void)n_in; (void)out_size; (void)ws_size;
    const float* x     = (const float*)d_in[0];
    const float* W_in  = (const float*)d_in[1];
    const float* cw    = (const float*)d_in[2];
    const float* cb    = (const float*)d_in[3];
    const float* W_x   = (const float*)d_in[4];
    const float* W_dt  = (const float*)d_in[5];
    const float* b_dt  = (const float*)d_in[6];
    const float* W_out = (const float*)d_in[7];
    const float* A_log = (const float*)d_in[8];
    float* out = (float*)d_out;

    float* ws = (float*)d_ws;
    const size_t MI = 1024 * 1024;
    // f32 regions
    float* u0   = ws;                 // [0,8Mi)   u0, then dT, then Aout planes
    float* sres = ws + 8*MI;          // [8,16Mi)
    float* uct  = ws + 16*MI;         // [16,24Mi) (X/W f16 planes live here pre-conv)
    float* y    = ws + 24*MI;         // [24,32Mi) part -> y
    float* part = y;
    float* dtin = ws + 32*MI;         // 64Ki
    float* Bm   = dtin + 65536;       // 64Ki
    float* Cv   = Bm + 65536;         // 4Ki
    float* WxT  = Cv + 4096;          // 66Ki
    float* dT   = u0;
    // f16 planes, phase 1 (gemm1 inputs) — over [16,24Mi), dead after gemm1
    f16* Xhi = (f16*)(ws + 16*MI);
    f16* Xlo = (f16*)(ws + 18*MI);
    f16* Whi = (f16*)(ws + 20*MI);
    f16* Wlo = (f16*)(ws + 22*MI);
    // f16 planes, phase 2 (gemmout inputs) — over dead u0/dT and uct
    f16* AoH = (f16*)(ws + 0);        // 8Mi f16
    f16* AoL = (f16*)(ws + 4*MI);
    f16* WoH = (f16*)(ws + 16*MI);    // 2Mi f16
    f16* WoL = (f16*)(ws + 17*MI);

    k_wxt      <<<dim3((33*INR + 255)/256), 256, 0, stream>>>(W_x, WxT);
    k_cvt_pair <<<dim3(2048), 256, 0, stream>>>(x,    Xhi, Xlo, 524288);
    k_cvt_pair <<<dim3(2048), 256, 0, stream>>>(W_in, Whi, Wlo, 524288);
    k_gemm_split<<<dim3(64, 32), 256, 0, stream>>>(Xhi, Xlo, Whi, Wlo,
                                                   DIMM, 1, INR, u0, sres);
    k_conv     <<<dim3(32, 32, 2), 256, 0, stream>>>(u0, cw, cb, uct);
    k_ssm_part <<<dim3(8, 16, 2), 256, 0, stream>>>(uct, WxT, part);
    k_ssm_reduce<<<dim3((33*TOKS + 255)/256), 256, 0, stream>>>(part, dtin, Bm, Cv);
    k_delta    <<<dim3(32, 64), 256, 0, stream>>>(dtin, W_dt, b_dt, dT);
    k_scan     <<<dim3(128, 2), 256, 0, stream>>>(dT, uct, Bm, Cv, A_log, y);
    k_cvt_mul  <<<dim3(4096), 256, 0, stream>>>(y, sres, AoH, AoL, 1048576);
    k_cvt_pair <<<dim3(1024), 256, 0, stream>>>(W_out, WoH, WoL, 262144);
    k_gemm_split<<<dim3(16, 32), 256, 0, stream>>>(AoH, AoL, WoH, WoL,
                                                   INR, 0, DIMM, out, nullptr);
}

// Round 4
// 405.124 us; speedup vs baseline: 2.9930x; 1.8222x over previous
//
#include <hip/hip_runtime.h>
#include <math.h>

#define SEQL   2048
#define DIMM   1024
#define NST    16
#define INR    2048
#define TOKS   4096   // BATCH*SEQL
#define LCH    256    // scan chunk length
#define NCH    8      // chunks per sequence

typedef _Float16 f16;
typedef _Float16 f16x8 __attribute__((ext_vector_type(8)));
typedef float    f32x4 __attribute__((ext_vector_type(4)));

__device__ __forceinline__ int swz(int r) { return (r & 3) ^ ((r >> 2) & 3); }

#define GLDS(SRC, DST) __builtin_amdgcn_global_load_lds( \
    (const __attribute__((address_space(1))) void*)(SRC), \
    (__attribute__((address_space(3))) void*)(DST), 16, 0, 0)

// ------------------------------------------------------------------
// W_x (33 x INR) -> W_xT (INR x 33)
__global__ __launch_bounds__(256) void k_wxt(const float* __restrict__ Wx,
                                             float* __restrict__ WxT)
{
    int i = blockIdx.x * 256 + threadIdx.x;
    if (i < 33 * INR) {
        int j = i / INR, ch = i % INR;
        WxT[ch * 33 + j] = Wx[i];
    }
}

// ------------------------------------------------------------------
// fp32 -> (hi fp16, lo fp16 scaled by 2048)
__global__ __launch_bounds__(256) void k_cvt_pair(const float* __restrict__ in,
        f16* __restrict__ hi, f16* __restrict__ lo, int n8)
{
    int i = blockIdx.x * 256 + threadIdx.x;
    if (i >= n8) return;
    const float4* p = (const float4*)(in + (size_t)i * 8);
    float4 a = p[0], b = p[1];
    float v[8] = {a.x, a.y, a.z, a.w, b.x, b.y, b.z, b.w};
    f16x8 H, L;
    #pragma unroll
    for (int j = 0; j < 8; ++j) {
        f16 h = (f16)v[j];
        float r = v[j] - (float)h;
        H[j] = h;
        L[j] = (f16)(r * 2048.f);
    }
    *(f16x8*)(hi + (size_t)i * 8) = H;
    *(f16x8*)(lo + (size_t)i * 8) = L;
}

// same, but input = y * sres (fused elementwise product)
__global__ __launch_bounds__(256) void k_cvt_mul(const float* __restrict__ ya,
        const float* __restrict__ sa, f16* __restrict__ hi, f16* __restrict__ lo,
        int n8)
{
    int i = blockIdx.x * 256 + threadIdx.x;
    if (i >= n8) return;
    const float4* py = (const float4*)(ya + (size_t)i * 8);
    const float4* ps = (const float4*)(sa + (size_t)i * 8);
    float4 a = py[0], b = py[1], c = ps[0], d = ps[1];
    float v[8] = {a.x*c.x, a.y*c.y, a.z*c.z, a.w*c.w,
                  b.x*d.x, b.y*d.y, b.z*d.z, b.w*d.w};
    f16x8 H, L;
    #pragma unroll
    for (int j = 0; j < 8; ++j) {
        f16 h = (f16)v[j];
        float r = v[j] - (float)h;
        H[j] = h;
        L[j] = (f16)(r * 2048.f);
    }
    *(f16x8*)(hi + (size_t)i * 8) = H;
    *(f16x8*)(lo + (size_t)i * 8) = L;
}

// ------------------------------------------------------------------
// Split-fp16 MFMA GEMM (NT): C[M][N] = A[M][K] * B[N][K]^T in ~fp32 accuracy.
__global__ __launch_bounds__(256, 3) void k_gemm_split(
        const f16* __restrict__ Ah, const f16* __restrict__ Al,
        const f16* __restrict__ Bh, const f16* __restrict__ Bl,
        int K, int epi, int Nst,
        float* __restrict__ out0, float* __restrict__ out1)
{
    const int AHI = 0, ALO = 4096, BHI = 8192, BLO = 10240;
    __shared__ alignas(16) f16 SM[12288];   // 24 KB

    const int tid = threadIdx.x;
    const int l   = tid & 63;
    const int w   = tid >> 6;
    const int wm  = (w >> 1) * 64;
    const int wn  = (w & 1) * 32;
    const int lr  = l & 15;
    const int kg  = l >> 4;
    const int m0  = blockIdx.y * 128;
    const int n0  = blockIdx.x * 64;

    const int srow = l >> 2;
    const int sc   = (l & 3) ^ swz(srow);
    const int w16  = w * 16;
    const int fo   = lr * 32 + (kg ^ swz(lr)) * 8;

    f32x4 acc0[4][2], acc1[4][2];
    #pragma unroll
    for (int mi = 0; mi < 4; ++mi)
        #pragma unroll
        for (int ni = 0; ni < 2; ++ni) {
            acc0[mi][ni] = (f32x4){0.f, 0.f, 0.f, 0.f};
            acc1[mi][ni] = (f32x4){0.f, 0.f, 0.f, 0.f};
        }

    for (int k0 = 0; k0 < K; k0 += 32) {
        __syncthreads();
        #pragma unroll
        for (int q = 0; q < 2; ++q) {
            const int rl = q * 64 + w16 + srow;
            const size_t go = (size_t)(m0 + rl) * K + k0 + sc * 8;
            GLDS(Ah + go, &SM[AHI + (q * 64 + w16) * 32]);
            GLDS(Al + go, &SM[ALO + (q * 64 + w16) * 32]);
        }
        {
            const int rl = w16 + srow;
            const size_t go = (size_t)(n0 + rl) * K + k0 + sc * 8;
            GLDS(Bh + go, &SM[BHI + w16 * 32]);
            GLDS(Bl + go, &SM[BLO + w16 * 32]);
        }
        __syncthreads();

        f16x8 ah[4], al4[4], bh[2], bl[2];
        #pragma unroll
        for (int mi = 0; mi < 4; ++mi) {
            int off = (wm + mi * 16) * 32 + fo;
            ah[mi]  = *(const f16x8*)&SM[AHI + off];
            al4[mi] = *(const f16x8*)&SM[ALO + off];
        }
        #pragma unroll
        for (int ni = 0; ni < 2; ++ni) {
            int off = (wn + ni * 16) * 32 + fo;
            bh[ni] = *(const f16x8*)&SM[BHI + off];
            bl[ni] = *(const f16x8*)&SM[BLO + off];
        }
        #pragma unroll
        for (int mi = 0; mi < 4; ++mi)
            #pragma unroll
            for (int ni = 0; ni < 2; ++ni) {
                acc0[mi][ni] = __builtin_amdgcn_mfma_f32_16x16x32_f16(
                                   ah[mi], bh[ni], acc0[mi][ni], 0, 0, 0);
                acc1[mi][ni] = __builtin_amdgcn_mfma_f32_16x16x32_f16(
                                   ah[mi], bl[ni], acc1[mi][ni], 0, 0, 0);
                acc1[mi][ni] = __builtin_amdgcn_mfma_f32_16x16x32_f16(
                                   al4[mi], bh[ni], acc1[mi][ni], 0, 0, 0);
            }
    }

    const int r0 = (l >> 4) * 4;
    #pragma unroll
    for (int mi = 0; mi < 4; ++mi)
        #pragma unroll
        for (int ni = 0; ni < 2; ++ni) {
            const int col = n0 + wn + ni * 16 + (l & 15);
            #pragma unroll
            for (int rr = 0; rr < 4; ++rr) {
                const int row = m0 + wm + mi * 16 + r0 + rr;
                float v = acc0[mi][ni][rr] + acc1[mi][ni][rr] * (1.0f / 2048.0f);
                if (epi) {
                    if (col < INR) {
                        out0[(size_t)row * INR + col] = v;
                    } else {
                        float s = v / (1.f + __expf(-v));
                        out1[(size_t)row * INR + (col - INR)] = s;
                    }
                } else {
                    out0[(size_t)row * Nst + col] = v;
                }
            }
        }
}

// ------------------------------------------------------------------
// Depthwise causal conv (K=4) + bias; u0 [tok][ch] -> uct [b][ch][t]
__global__ __launch_bounds__(256) void k_conv(const float* __restrict__ u0,
        const float* __restrict__ cw, const float* __restrict__ cb,
        float* __restrict__ uct)
{
    __shared__ float S[67][65];
    const int tid = threadIdx.x;
    const int ch0 = blockIdx.x * 64;
    const int t0  = blockIdx.y * 64;
    const int b   = blockIdx.z;
    const int ci  = tid & 63;
    for (int r = tid >> 6; r < 67; r += 4) {
        int t = t0 - 3 + r;
        S[r][ci] = (t < 0) ? 0.f : u0[((size_t)b*SEQL + t)*INR + ch0 + ci];
    }
    __syncthreads();
    const int ti = tid & 63;
    const int cq = tid >> 6;
    #pragma unroll
    for (int q = 0; q < 16; ++q) {
        int c  = cq + q*4;
        int ch = ch0 + c;
        float w0 = cw[ch*4+0], w1 = cw[ch*4+1], w2 = cw[ch*4+2], w3 = cw[ch*4+3];
        float acc = cb[ch]
            + w0*S[ti+0][c] + w1*S[ti+1][c] + w2*S[ti+2][c] + w3*S[ti+3][c];
        uct[((size_t)b*INR + ch)*SEQL + t0 + ti] = acc;
    }
}

// ------------------------------------------------------------------
// ssm = u @ W_x.T : reduce over channels, 16-way split -> partials.
__global__ __launch_bounds__(256) void k_ssm_part(const float* __restrict__ uct,
        const float* __restrict__ WxT, float* __restrict__ part)
{
    const int t  = blockIdx.x * 256 + threadIdx.x;
    const int cs = blockIdx.y;                      // 0..15
    const int b  = blockIdx.z;
    const int ch0 = cs * 128;
    float acc[33];
    #pragma unroll
    for (int j = 0; j < 33; ++j) acc[j] = 0.f;
    const float* up = uct + ((size_t)b*INR + ch0)*SEQL + t;
    for (int c = 0; c < 128; ++c) {
        float uv = up[(size_t)c * SEQL];
        const float* wr = WxT + (size_t)(ch0 + c) * 33;
        #pragma unroll
        for (int j = 0; j < 33; ++j) acc[j] = fmaf(uv, wr[j], acc[j]);
    }
    #pragma unroll
    for (int j = 0; j < 33; ++j)
        part[(((size_t)j*16 + cs)*2 + b)*SEQL + t] = acc[j];
}

__global__ __launch_bounds__(256) void k_ssm_reduce(const float* __restrict__ part,
        float* __restrict__ dtin, float* __restrict__ Bm, float* __restrict__ Cv)
{
    int g = blockIdx.x * 256 + threadIdx.x;
    if (g >= 33 * TOKS) return;
    int j = g / TOKS, m = g % TOKS;
    int b = m >> 11, t = m & 2047;
    float s = 0.f;
    #pragma unroll
    for (int cs = 0; cs < 16; ++cs)
        s += part[(((size_t)j*16 + cs)*2 + b)*SEQL + t];
    if (j < 16)      dtin[m*16 + j] = s;
    else if (j < 32) Bm[m*16 + (j-16)] = s;
    else             Cv[m] = s;
}

// ------------------------------------------------------------------
// delta = softplus(dt_in @ W_dt.T + b_dt) -> dT [b][ch][t]
__global__ __launch_bounds__(256) void k_delta(const float* __restrict__ dtin,
        const float* __restrict__ Wdt, const float* __restrict__ bdt,
        float* __restrict__ dT)
{
    __shared__ float Ds[16][68];
    __shared__ float Ws[16][68];
    const int tid = threadIdx.x;
    const int c0 = blockIdx.x * 64;
    const int m0 = blockIdx.y * 64;
    const int r = tid >> 2, kq = (tid & 3) * 4;
    {
        float4 dv = *(const float4*)&dtin[(size_t)(m0 + r)*16 + kq];
        float4 wv = *(const float4*)&Wdt [(size_t)(c0 + r)*16 + kq];
        Ds[kq+0][r]=dv.x; Ds[kq+1][r]=dv.y; Ds[kq+2][r]=dv.z; Ds[kq+3][r]=dv.w;
        Ws[kq+0][r]=wv.x; Ws[kq+1][r]=wv.y; Ws[kq+2][r]=wv.z; Ws[kq+3][r]=wv.w;
    }
    __syncthreads();
    const int tx = tid & 15, ty = tid >> 4;
    float acc[4][4];
    #pragma unroll
    for (int i = 0; i < 4; ++i)
        #pragma unroll
        for (int j = 0; j < 4; ++j) acc[i][j] = 0.f;
    #pragma unroll
    for (int kk = 0; kk < 16; ++kk) {
        float4 a4 = *(const float4*)&Ds[kk][ty*4];
        float4 b4 = *(const float4*)&Ws[kk][tx*4];
        float a[4] = {a4.x, a4.y, a4.z, a4.w};
        float wv[4] = {b4.x, b4.y, b4.z, b4.w};
        #pragma unroll
        for (int i = 0; i < 4; ++i)
            #pragma unroll
            for (int j = 0; j < 4; ++j)
                acc[i][j] = fmaf(a[i], wv[j], acc[i][j]);
    }
    const int b = m0 >> 11;
    const int tbase = (m0 & 2047) + ty*4;
    #pragma unroll
    for (int j = 0; j < 4; ++j) {
        int ch = c0 + tx*4 + j;
        float bias = bdt[ch];
        float4 o;
        o.x = log1pf(__expf(acc[0][j] + bias));
        o.y = log1pf(__expf(acc[1][j] + bias));
        o.z = log1pf(__expf(acc[2][j] + bias));
        o.w = log1pf(__expf(acc[3][j] + bias));
        *(float4*)&dT[((size_t)b*INR + ch)*SEQL + tbase] = o;
    }
}

// ------------------------------------------------------------------
// Chunked scan, pass 1: per-chunk local scan -> h_out, E = exp(A*sum(d)).
// Block: 16 channels x 16 states; grid (128, NCH, 2).
__global__ __launch_bounds__(256) void k_scan1(const float* __restrict__ dT,
        const float* __restrict__ uct, const float* __restrict__ Bm,
        const float* __restrict__ Alog,
        float* __restrict__ hout, float* __restrict__ Eag)
{
    __shared__ float dS[16][68];
    __shared__ float uS[16][68];
    __shared__ float bT[16][68];   // B transposed: [s][t]
    const int tid = threadIdx.x;
    const int g = tid >> 4, s = tid & 15;
    const int ch0 = blockIdx.x * 16;
    const int c   = blockIdx.y;
    const int b   = blockIdx.z;
    const int ch  = ch0 + g;
    const int tbase = c * LCH;
    const size_t mb = (size_t)b * SEQL;
    const float A = -__expf(Alog[ch*NST + s]);
    float h = 0.f, Dsum = 0.f;
    const int row = tid >> 4, col4 = (tid & 15) * 4;
    const int sB = tid & 15, tq = tid >> 4;
    const float* dRow = dT  + ((size_t)b*INR + ch0 + row)*SEQL + tbase;
    const float* uRow = uct + ((size_t)b*INR + ch0 + row)*SEQL + tbase;

    for (int t0 = 0; t0 < LCH; t0 += 64) {
        __syncthreads();
        *(float4*)&dS[row][col4] = *(const float4*)&dRow[t0 + col4];
        *(float4*)&uS[row][col4] = *(const float4*)&uRow[t0 + col4];
        #pragma unroll
        for (int k = 0; k < 4; ++k)
            bT[sB][tq*4 + k] = Bm[(mb + tbase + t0 + tq*4 + k)*16 + sB];
        __syncthreads();
        #pragma unroll
        for (int q = 0; q < 16; ++q) {
            float4 d4 = *(const float4*)&dS[g][q*4];
            float4 u4 = *(const float4*)&uS[g][q*4];
            float4 b4 = *(const float4*)&bT[s][q*4];
            h = fmaf(h, __expf(d4.x*A), u4.x*b4.x);
            h = fmaf(h, __expf(d4.y*A), u4.y*b4.y);
            h = fmaf(h, __expf(d4.z*A), u4.z*b4.z);
            h = fmaf(h, __expf(d4.w*A), u4.w*b4.w);
            Dsum += (d4.x + d4.y) + (d4.z + d4.w);
        }
    }
    size_t idx = (((size_t)(b*NCH + c))*INR + ch)*NST + s;
    hout[idx] = h;
    Eag[idx]  = __expf(A * Dsum);
}

// ------------------------------------------------------------------
// Chunked scan, pass 2: serial combine over the NCH chunk aggregates.
// hin may alias hout (in-place).
__global__ __launch_bounds__(256) void k_scan2(const float* __restrict__ hout,
        const float* __restrict__ Eag, float* __restrict__ hin)
{
    int p = blockIdx.x * 256 + threadIdx.x;   // over 2*INR*NST
    if (p >= 2 * INR * NST) return;
    int b = p >> 15;
    int r = p & 32767;
    float h = 0.f;
    for (int c = 0; c < NCH; ++c) {
        size_t idx = ((size_t)(b*NCH + c)) * (INR*NST) + r;
        float E  = Eag[idx];
        float ho = hout[idx];
        hin[idx] = h;
        h = h * E + ho;
    }
}

// ------------------------------------------------------------------
// Chunked scan, pass 3: local scan seeded with h_in; deferred 16-state
// reduction via LDS (stride-17) every 16 steps -> y.
__global__ __launch_bounds__(256) void k_scan3(const float* __restrict__ dT,
        const float* __restrict__ uct, const float* __restrict__ Bm,
        const float* __restrict__ Cv, const float* __restrict__ Alog,
        const float* __restrict__ hin, float* __restrict__ Y)
{
    __shared__ float dS[16][68];
    __shared__ float uS[16][68];
    __shared__ float bT[16][68];
    __shared__ float cS[64];
    __shared__ float hS[16*272];   // [step][g*17+s]
    const int tid = threadIdx.x;
    const int g = tid >> 4, s = tid & 15;
    const int ch0 = blockIdx.x * 16;
    const int c   = blockIdx.y;
    const int b   = blockIdx.z;
    const int ch  = ch0 + g;
    const int tbase = c * LCH;
    const size_t mb = (size_t)b * SEQL;
    const float A = -__expf(Alog[ch*NST + s]);
    float h = hin[(((size_t)(b*NCH + c))*INR + ch)*NST + s];
    const int row = tid >> 4, col4 = (tid & 15) * 4;
    const int sB = tid & 15, tq = tid >> 4;
    const int ci = tid & 15, tw = tid >> 4;   // reduce-phase roles
    const float* dRow = dT  + ((size_t)b*INR + ch0 + row)*SEQL + tbase;
    const float* uRow = uct + ((size_t)b*INR + ch0 + row)*SEQL + tbase;

    for (int t0 = 0; t0 < LCH; t0 += 64) {
        __syncthreads();
        *(float4*)&dS[row][col4] = *(const float4*)&dRow[t0 + col4];
        *(float4*)&uS[row][col4] = *(const float4*)&uRow[t0 + col4];
        #pragma unroll
        for (int k = 0; k < 4; ++k)
            bT[sB][tq*4 + k] = Bm[(mb + tbase + t0 + tq*4 + k)*16 + sB];
        if (tid < 64) cS[tid] = Cv[mb + tbase + t0 + tid];
        __syncthreads();
        #pragma unroll
        for (int sub = 0; sub < 4; ++sub) {
            #pragma unroll
            for (int q = 0; q < 4; ++q) {
                float4 d4 = *(const float4*)&dS[g][sub*16 + q*4];
                float4 u4 = *(const float4*)&uS[g][sub*16 + q*4];
                float4 b4 = *(const float4*)&bT[s][sub*16 + q*4];
                h = fmaf(h, __expf(d4.x*A), u4.x*b4.x);
                hS[(q*4+0)*272 + g*17 + s] = h;
                h = fmaf(h, __expf(d4.y*A), u4.y*b4.y);
                hS[(q*4+1)*272 + g*17 + s] = h;
                h = fmaf(h, __expf(d4.z*A), u4.z*b4.z);
                hS[(q*4+2)*272 + g*17 + s] = h;
                h = fmaf(h, __expf(d4.w*A), u4.w*b4.w);
                hS[(q*4+3)*272 + g*17 + s] = h;
            }
            __syncthreads();
            float v = 0.f;
            #pragma unroll
            for (int ss = 0; ss < 16; ++ss)
                v += hS[tw*272 + ci*17 + ss];
            const int tl = sub*16 + tw;     // tile-local token 0..63
            Y[(mb + tbase + t0 + tl)*INR + ch0 + ci] = v * cS[tl];
            __syncthreads();
        }
    }
}

// ------------------------------------------------------------------
extern "C" void kernel_launch(void* const* d_in, const int* in_sizes, int n_in,
                              void* d_out, int out_size, void* d_ws, size_t ws_size,
                              hipStream_t stream)
{
    (void)in_sizes; (void)n_in; (void)out_size; (void)ws_size;
    const float* x     = (const float*)d_in[0];
    const float* W_in  = (const float*)d_in[1];
    const float* cw    = (const float*)d_in[2];
    const float* cb    = (const float*)d_in[3];
    const float* W_x   = (const float*)d_in[4];
    const float* W_dt  = (const float*)d_in[5];
    const float* b_dt  = (const float*)d_in[6];
    const float* W_out = (const float*)d_in[7];
    const float* A_log = (const float*)d_in[8];
    float* out = (float*)d_out;

    float* ws = (float*)d_ws;
    const size_t MI = 1024 * 1024;
    float* u0   = ws;                 // [0,8Mi)   u0 -> dT -> AoH/AoL planes
    float* sres = ws + 8*MI;          // [8,16Mi)
    float* uct  = ws + 16*MI;         // [16,24Mi)
    float* y    = ws + 24*MI;         // [24,32Mi) part -> y
    float* part = y;
    float* dtin = ws + 32*MI;         // 64Ki
    float* Bm   = dtin + 65536;       // 64Ki
    float* Cv   = Bm + 65536;         // 4Ki
    float* WxT  = Cv + 4096;          // 66Ki
    float* dT   = u0;
    // chunk-scan aggregates live in d_out (dead until final GEMM): 1Mi floats
    float* houtb = out;               // 512Ki floats (hout, then hin in-place)
    float* Eag   = out + 524288;      // 512Ki floats
    // f16 planes, phase 1 (gemm1 inputs) — over [16,24Mi), dead after gemm1
    f16* Xhi = (f16*)(ws + 16*MI);
    f16* Xlo = (f16*)(ws + 18*MI);
    f16* Whi = (f16*)(ws + 20*MI);
    f16* Wlo = (f16*)(ws + 22*MI);
    // f16 planes, phase 2 (gemmout inputs) — over dead u0/dT and uct
    f16* AoH = (f16*)(ws + 0);
    f16* AoL = (f16*)(ws + 4*MI);
    f16* WoH = (f16*)(ws + 16*MI);
    f16* WoL = (f16*)(ws + 17*MI);

    k_wxt      <<<dim3((33*INR + 255)/256), 256, 0, stream>>>(W_x, WxT);
    k_cvt_pair <<<dim3(2048), 256, 0, stream>>>(x,    Xhi, Xlo, 524288);
    k_cvt_pair <<<dim3(2048), 256, 0, stream>>>(W_in, Whi, Wlo, 524288);
    k_gemm_split<<<dim3(64, 32), 256, 0, stream>>>(Xhi, Xlo, Whi, Wlo,
                                                   DIMM, 1, INR, u0, sres);
    k_conv     <<<dim3(32, 32, 2), 256, 0, stream>>>(u0, cw, cb, uct);
    k_ssm_part <<<dim3(8, 16, 2), 256, 0, stream>>>(uct, WxT, part);
    k_ssm_reduce<<<dim3((33*TOKS + 255)/256), 256, 0, stream>>>(part, dtin, Bm, Cv);
    k_delta    <<<dim3(32, 64), 256, 0, stream>>>(dtin, W_dt, b_dt, dT);
    k_scan1    <<<dim3(128, NCH, 2), 256, 0, stream>>>(dT, uct, Bm, A_log, houtb, Eag);
    k_scan2    <<<dim3(256), 256, 0, stream>>>(houtb, Eag, houtb);
    k_scan3    <<<dim3(128, NCH, 2), 256, 0, stream>>>(dT, uct, Bm, Cv, A_log, houtb, y);
    k_cvt_mul  <<<dim3(4096), 256, 0, stream>>>(y, sres, AoH, AoL, 1048576);
    k_cvt_pair <<<dim3(1024), 256, 0, stream>>>(W_out, WoH, WoL, 262144);
    k_gemm_split<<<dim3(16, 32), 256, 0, stream>>>(AoH, AoL, WoH, WoL,
                                                   INR, 0, DIMM, out, nullptr);
}